// Round 1
// baseline (204.690 us; speedup 1.0000x reference)
//
#include <hip/hip_runtime.h>

// InstanceRecognizerReconstructor: multi-scale overlapping-window score
// scatter + coverage normalization.
//
// out[b,s,y,x] = (sum over windows (wy,wx) of scale SCALES[s] covering (y,x)
//                 of sim_s[b,wy,wx]) / (#covering windows)
//
// Window (wy,wx) covers [wy*8, wy*8+scale) x [wx*8, wx*8+scale).
// Separable: T[wy][x] = sum_wx sim[wy][wx]  (horizontal), then
//            out[y][x] = sum_wy T[wy][x]    (vertical), count = ny(y)*nx(x).
//
// Coverage predicate collapses: for xb = x>>3, window wx = xb - j covers x
// for ALL j in [0,K) (K = scale/8), needing only 0 <= wx < XW.  (Proof:
// (x&7) < 8*(K-j) holds since (x&7) <= 7 and K-j >= 1.)

constexpr int HH = 96;
constexpr int WW = 128;

template <int SCALE, int YW, int XW>
__device__ __forceinline__ void run_scale(const float* __restrict__ sim,
                                          float* __restrict__ outPlane,
                                          float* s_sim, float* s_T, int b) {
  constexpr int K = SCALE / 8;
  constexpr int NSIM = YW * XW;
  const int tid = threadIdx.x;

  // Stage this batch's window scores (<= 165 floats) into LDS.
  if (tid < NSIM) s_sim[tid] = sim[(size_t)b * NSIM + tid];
  __syncthreads();

  // Phase 1: horizontal windowed sums T[wy][x], wy in [0,YW), x in [0,128).
  for (int idx = tid; idx < YW * WW; idx += 256) {
    const int wy = idx >> 7;          // row of window grid
    const int x  = idx & (WW - 1);
    const int xb = x >> 3;
    float t = 0.f;
#pragma unroll
    for (int j = 0; j < K; ++j) {
      const int wx = xb - j;
      t += (wx >= 0 && wx < XW) ? s_sim[wy * XW + wx] : 0.f;
    }
    s_T[idx] = t;
  }
  __syncthreads();

  // Phase 2: vertical sums + count normalize; float4 coalesced stores.
  const float4* Tf4 = reinterpret_cast<const float4*>(s_T);
  float4* outF4 = reinterpret_cast<float4*>(outPlane);
  for (int i = tid; i < HH * (WW / 4); i += 256) {
    const int y  = i >> 5;            // output row
    const int c  = i & 31;            // float4 chunk within row
    const int yb = y >> 3;
    const int xb = c >> 1;            // (c*4)>>3 ; uniform across the 4 lanes' elems
    float4 acc = make_float4(0.f, 0.f, 0.f, 0.f);
#pragma unroll
    for (int j = 0; j < K; ++j) {
      const int wy = yb - j;
      if (wy >= 0 && wy < YW) {
        const float4 v = Tf4[wy * (WW / 4) + c];
        acc.x += v.x; acc.y += v.y; acc.z += v.z; acc.w += v.w;
      }
    }
    const int ny = min(yb, YW - 1) - max(0, yb - K + 1) + 1;
    const int nx = min(xb, XW - 1) - max(0, xb - K + 1) + 1;
    const float cnt = (float)(ny * nx);
    float4 r;
    r.x = acc.x / cnt;
    r.y = acc.y / cnt;
    r.z = acc.z / cnt;
    r.w = acc.w / cnt;
    outF4[i] = r;
  }
}

__global__ __launch_bounds__(256) void irr_score_kernel(
    const float* __restrict__ s0, const float* __restrict__ s1,
    const float* __restrict__ s2, const float* __restrict__ s3,
    float* __restrict__ out) {
  // LDS sized for the worst case (scale 16: NSIM=165, YW=11).
  __shared__ float s_sim[176];
  __shared__ float s_T[11 * WW];

  const int blk = blockIdx.x;
  const int b = blk >> 2;   // batch
  const int s = blk & 3;    // scale index (block-uniform -> no divergence)
  float* plane = out + (size_t)(b * 4 + s) * (HH * WW);
  switch (s) {
    case 0: run_scale<16, 11, 15>(s0, plane, s_sim, s_T, b); break;
    case 1: run_scale<24, 10, 14>(s1, plane, s_sim, s_T, b); break;
    case 2: run_scale<32,  9, 13>(s2, plane, s_sim, s_T, b); break;
    case 3: run_scale<48,  7, 11>(s3, plane, s_sim, s_T, b); break;
  }
}

extern "C" void kernel_launch(void* const* d_in, const int* in_sizes, int n_in,
                              void* d_out, int out_size, void* d_ws, size_t ws_size,
                              hipStream_t stream) {
  const float* s0 = (const float*)d_in[0];  // (B,1,11,15)
  const float* s1 = (const float*)d_in[1];  // (B,1,10,14)
  const float* s2 = (const float*)d_in[2];  // (B,1, 9,13)
  const float* s3 = (const float*)d_in[3];  // (B,1, 7,11)
  float* out = (float*)d_out;               // (B,4,96,128)

  const int B = in_sizes[0] / (11 * 15);
  dim3 grid(4 * B), block(256);
  irr_score_kernel<<<grid, block, 0, stream>>>(s0, s1, s2, s3, out);
}

// Round 2
// 200.002 us; speedup vs baseline: 1.0234x; 1.0234x over previous
//
#include <hip/hip_runtime.h>

// InstanceRecognizerReconstructor: multi-scale overlapping-window score
// scatter + coverage normalization.
//
// out[b,s,y,x] = (sum over windows (wy,wx) of scale SCALES[s] covering (y,x)
//                 of sim_s[b,wy,wx]) / (#covering windows)
//
// Separable transposed sum-pooling:
//   T[wy][x] = sum_wx sim[wy][wx]   (horizontal, <=K terms, K = scale/8)
//   out[y][x] = sum_wy T[wy][x]     (vertical,  <=K terms)
//   count(y,x) = ny(yb)*nx(xb)      (separable, yb=y>>3, xb=x>>3)
// Coverage predicate collapses to 0 <= wb - j < {XW,YW} for j in [0,K)
// because scale is a multiple of STRIDE=8.
//
// Phase-2 index algebra: i = tid + 256k  =>  y = (tid>>5) + 8k, so yb == k
// exactly (tid>>5 <= 7). Hence ny is a COMPILE-TIME constant per unrolled k,
// and each thread's c/xb/nx are loop-invariant.

constexpr int HH = 96;
constexpr int WW = 128;

template <int SCALE, int YW, int XW>
__device__ __forceinline__ void run_scale(const float* __restrict__ sim,
                                          float* __restrict__ outPlane,
                                          float* __restrict__ s_sim,
                                          float* __restrict__ s_T, int b) {
  constexpr int K = SCALE / 8;
  constexpr int NSIM = YW * XW;
  const int tid = threadIdx.x;

  // Stage this batch's window scores (<=165 floats) into LDS.
  if (tid < NSIM) s_sim[tid] = sim[(size_t)b * NSIM + tid];
  __syncthreads();

  // ---- Phase 1: horizontal windowed sums T[wy][x] ----
  constexpr int P1 = YW * WW;
#pragma unroll
  for (int base = 0; base < P1; base += 256) {
    const int idx = base + tid;
    if ((base + 256 <= P1) || (idx < P1)) {   // tail check folds away when full
      const int wy = idx >> 7;                // window-grid row
      const int xb = (idx & (WW - 1)) >> 3;
      float t = 0.f;
#pragma unroll
      for (int j = 0; j < K; ++j) {
        const int wx = xb - j;
        t += (wx >= 0 && wx < XW) ? s_sim[wy * XW + wx] : 0.f;
      }
      s_T[idx] = t;
    }
  }
  __syncthreads();

  // ---- Phase 2: vertical sums + count normalize; float4 coalesced stores ----
  const int c  = tid & 31;                    // float4 chunk within row
  const int xb = c >> 1;                      // 8-px block (uniform over the 4 elems)
  const int nx = min(xb, XW - 1) - max(0, xb - K + 1) + 1;
  const float fnx = (float)nx;
  const float4* Tf4 = reinterpret_cast<const float4*>(s_T);
  float4* outF4 = reinterpret_cast<float4*>(outPlane) + tid;

#pragma unroll
  for (int k = 0; k < HH / 8; ++k) {          // yb == k (see header comment)
    float4 acc = make_float4(0.f, 0.f, 0.f, 0.f);
#pragma unroll
    for (int j = 0; j < K; ++j) {
      const int wy = k - j;                   // compile-time after unroll
      if (wy >= 0 && wy < YW) {
        const float4 v = Tf4[wy * (WW / 4) + c];
        acc.x += v.x; acc.y += v.y; acc.z += v.z; acc.w += v.w;
      }
    }
    const int ny = min(k, YW - 1) - max(0, k - K + 1) + 1;  // compile-time
    // count fits exactly in fp32; v_rcp_f32 is ~1 ulp (<<2e-3 accepted absmax)
    const float inv = __builtin_amdgcn_rcpf(fnx * (float)ny);
    float4 r;
    r.x = acc.x * inv; r.y = acc.y * inv; r.z = acc.z * inv; r.w = acc.w * inv;
    outF4[k * 256] = r;                       // 1 KB/wave contiguous stores
  }
}

__global__ __launch_bounds__(256) void irr_score_kernel(
    const float* __restrict__ s0, const float* __restrict__ s1,
    const float* __restrict__ s2, const float* __restrict__ s3,
    float* __restrict__ out) {
  __shared__ float s_sim[176];        // worst case NSIM=165 (scale 16)
  __shared__ float s_T[11 * WW];      // worst case YW=11

  const int blk = blockIdx.x;
  const int b = blk >> 2;             // batch
  const int s = blk & 3;              // scale index (block-uniform)
  float* plane = out + (size_t)(b * 4 + s) * (HH * WW);
  switch (s) {
    case 0: run_scale<16, 11, 15>(s0, plane, s_sim, s_T, b); break;
    case 1: run_scale<24, 10, 14>(s1, plane, s_sim, s_T, b); break;
    case 2: run_scale<32,  9, 13>(s2, plane, s_sim, s_T, b); break;
    case 3: run_scale<48,  7, 11>(s3, plane, s_sim, s_T, b); break;
  }
}

extern "C" void kernel_launch(void* const* d_in, const int* in_sizes, int n_in,
                              void* d_out, int out_size, void* d_ws, size_t ws_size,
                              hipStream_t stream) {
  const float* s0 = (const float*)d_in[0];  // (B,1,11,15)
  const float* s1 = (const float*)d_in[1];  // (B,1,10,14)
  const float* s2 = (const float*)d_in[2];  // (B,1, 9,13)
  const float* s3 = (const float*)d_in[3];  // (B,1, 7,11)
  float* out = (float*)d_out;               // (B,4,96,128)

  const int B = in_sizes[0] / (11 * 15);
  dim3 grid(4 * B), block(256);
  irr_score_kernel<<<grid, block, 0, stream>>>(s0, s1, s2, s3, out);
}